// Round 6
// baseline (181.708 us; speedup 1.0000x reference)
//
#include <hip/hip_runtime.h>
#include <hip/hip_bf16.h>
#include <stdint.h>

#define DEV __device__ __forceinline__

typedef __attribute__((ext_vector_type(8))) short bf16x8;
typedef __attribute__((ext_vector_type(4))) float f32x4;
typedef unsigned short u16;

// ---- async global->LDS, 16B per lane. lds dest must be wave-uniform base. ----
DEV void gload_lds16(const void* g, void* l) {
    typedef const __attribute__((address_space(1))) unsigned int* gp_t;
    typedef __attribute__((address_space(3))) unsigned int* lp_t;
    __builtin_amdgcn_global_load_lds((gp_t)(uintptr_t)g, (lp_t)(uint32_t)(uintptr_t)l, 16, 0, 0);
}

DEV u16 f2bf(float x) {
    union { __hip_bfloat16 h; u16 u; } c;
    c.h = __float2bfloat16(x);
    return c.u;
}
// packed f32x2 -> bf16x2 (v_cvt_pk_bf16_f32 path)
DEV unsigned pack2bf(float a, float b) {
    union { __hip_bfloat162 h2; unsigned u; } cv;
    cv.h2 = __float22bfloat162_rn(make_float2(a, b));
    return cv.u;
}

// ============================ cast fp32 -> bf16 ============================
__global__ void cast_kernel(const float* __restrict__ src, u16* __restrict__ dst, int n8) {
    int stride = gridDim.x * blockDim.x;
    for (int i = blockIdx.x * blockDim.x + threadIdx.x; i < n8; i += stride) {
        const float4* s = (const float4*)src + (size_t)i * 2;
        float4 a = s[0], b = s[1];
        union { u16 u[8]; uint4 v; } o;
        o.u[0] = f2bf(a.x); o.u[1] = f2bf(a.y); o.u[2] = f2bf(a.z); o.u[3] = f2bf(a.w);
        o.u[4] = f2bf(b.x); o.u[5] = f2bf(b.y); o.u[6] = f2bf(b.z); o.u[7] = f2bf(b.w);
        *((uint4*)dst + i) = o.v;
    }
}

// ============================ projection GEMM ==============================
DEV void gemm_body(const u16* A, const u16* Bw, const float* bias, int bias_row,
                   u16* out, int out_pitch)
{
    __shared__ char smA[16384];
    __shared__ char smB[16384];
    const int lane = threadIdx.x & 63;
    const int w    = threadIdx.x >> 6;
    const int wr   = w >> 1, wc = w & 1;
    const int l15  = lane & 15, lg = lane >> 4;

    f32x4 acc[4][4] = {};
    const char* ag = (const char*)A;
    const char* bg = (const char*)Bw;

    for (int kt = 0; kt < 4; ++kt) {
        __syncthreads();
        #pragma unroll
        for (int c = 0; c < 8; ++c) {
            int ch    = w * 8 + c;
            int loc   = ch & 15;
            int p     = loc * 1024 + lane * 16;
            int row   = p >> 7;
            int inner = (p & 127) ^ ((row & 7) << 4);
            const char* src = (ch < 16 ? ag : bg) + row * 512 + kt * 128 + inner;
            char* dst = (ch < 16 ? smA : smB) + loc * 1024;
            gload_lds16(src, dst);
        }
        __syncthreads();
        #pragma unroll
        for (int ks = 0; ks < 2; ++ks) {
            bf16x8 af[4], bfr[4];
            #pragma unroll
            for (int mi = 0; mi < 4; ++mi) {
                int row = wr * 64 + mi * 16 + l15;
                af[mi] = *(const bf16x8*)(smA + ((row * 128 + ks * 64 + lg * 16) ^ ((row & 7) << 4)));
            }
            #pragma unroll
            for (int ni = 0; ni < 4; ++ni) {
                int row = wc * 64 + ni * 16 + l15;
                bfr[ni] = *(const bf16x8*)(smB + ((row * 128 + ks * 64 + lg * 16) ^ ((row & 7) << 4)));
            }
            #pragma unroll
            for (int mi = 0; mi < 4; ++mi)
                #pragma unroll
                for (int ni = 0; ni < 4; ++ni)
                    acc[mi][ni] = __builtin_amdgcn_mfma_f32_16x16x32_bf16(af[mi], bfr[ni], acc[mi][ni], 0, 0, 0);
        }
    }
    #pragma unroll
    for (int mi = 0; mi < 4; ++mi) {
        #pragma unroll
        for (int ni = 0; ni < 4; ++ni) {
            int n_l  = wc * 64 + ni * 16 + l15;
            float bn = bias_row ? 0.f : bias[n_l];
            #pragma unroll
            for (int r = 0; r < 4; ++r) {
                int row  = wr * 64 + mi * 16 + lg * 4 + r;
                float bb = bias_row ? bias[row] : bn;
                out[(size_t)row * out_pitch + n_l] = f2bf(acc[mi][ni][r] + bb);
            }
        }
    }
}

__global__ __launch_bounds__(256) void proj_qk_kernel(
    const u16* xb, const u16* wqb, const u16* wkb,
    const float* bq, const float* bk, u16* Q, u16* K)
{
    int n0 = blockIdx.x * 128;
    int m0 = blockIdx.y * 128;
    bool isK = n0 >= 256;
    int  nl  = n0 & 255;
    gemm_body(xb + (size_t)m0 * 256, (isK ? wkb : wqb) + (size_t)nl * 256,
              (isK ? bk : bq) + nl, 0,
              (isK ? K : Q) + (size_t)m0 * 256 + nl, 256);
}

__global__ __launch_bounds__(256) void proj_v_kernel(
    const u16* wvb, const u16* xb, const float* bv, u16* Vt)
{
    int n0 = blockIdx.x * 128;
    int m0 = blockIdx.y * 128;
    gemm_body(wvb + (size_t)m0 * 256, xb + (size_t)n0 * 256, bv + m0, 1,
              Vt + (size_t)m0 * 32768 + n0, 32768);
}

// ============================ fused attention ==============================
// 4 waves x 16 q-rows = 64 q/block, grid 512 = 2 blocks/CU. KVBLK=32 dbuf.
// VALU-diet version: all LDS read addresses are 1 base VGPR + instruction
// immediates (K swizzle = (row&3)<<4, bits 4-5 only, so ks*64 / dt*1024 terms
// stay immediate-foldable); staging uses precomputed per-lane 32-bit offsets
// + uniform scalar base advance; bf16 pack via v_cvt_pk; QK chain split 4-way.
__global__ __launch_bounds__(256, 2) void attn_kernel(
    const u16* __restrict__ Q, const u16* __restrict__ K,
    const u16* __restrict__ Vt, float* __restrict__ out)
{
    __shared__ char sm[65536];
    // K tile t: sm + (t&1)*16384:         [32 kv][512B], byte ^= (row&3)<<4
    // V tile t: sm + 32768 + (t&1)*16384: [256 d][64B],  byte ^= ((row>>1)&3)<<4

    const int lane = threadIdx.x & 63;
    const int w    = threadIdx.x >> 6;
    const int l15  = lane & 15;
    const int lg   = lane >> 4;

    // XCD batch-confinement: XCD (lin%8) serves 2 batches -> K/V (4MB) L2-resident
    const int lin = blockIdx.y * 32 + blockIdx.x;
    const int b   = (lin & 7) * 2 + ((lin >> 3) & 1);
    const int qt  = lin >> 4;
    const size_t tokbase = (size_t)b * 2048;
    const int q0w = qt * 64 + w * 16;

    // Q fragments (B-operand): lane holds Q[q0w+l15][ks*32 + lg*8 + j]
    bf16x8 qf[8];
    {
        const char* qrow = (const char*)(Q + (tokbase + q0w + l15) * 256);
        #pragma unroll
        for (int ks = 0; ks < 8; ++ks)
            qf[ks] = *(const bf16x8*)(qrow + ks * 64 + lg * 16);
    }

    // ---- staging setup: per-lane invariant offsets, uniform per-tile base bump
    uint32_t goff[8];
    const char* gbase;   // uniform source base for tile 0
    int gstep;           // uniform source bytes per tile
    char* ldst;          // wave-uniform LDS dst base (buffer 0)
    if (w < 2) {         // waves 0,1 stage K (rows 0..31, 512B each)
        #pragma unroll
        for (int c = 0; c < 8; ++c) {
            int row = (w * 8 + c) * 2 + (lane >> 5);
            goff[c] = row * 512 + (((lane & 31) * 16) ^ ((row & 3) << 4));
        }
        gbase = (const char*)K + tokbase * 512;
        gstep = 32 * 512;
        ldst  = sm + w * 8192;
    } else {             // waves 2,3 stage Vt (256 d-rows x 64B slice)
        #pragma unroll
        for (int c = 0; c < 8; ++c) {
            int row = ((w - 2) * 8 + c) * 16 + (lane >> 2);
            goff[c] = row * 65536 + (((lane & 3) * 16) ^ (((row >> 1) & 3) << 4));
        }
        gbase = (const char*)Vt + tokbase * 2;
        gstep = 32 * 2;
        ldst  = sm + 32768 + (w - 2) * 8192;
    }
    auto stage = [&](int t) {
        const char* gb = gbase + (size_t)t * gstep;   // uniform (SALU)
        char* lb = ldst + ((t & 1) << 14);
        #pragma unroll
        for (int c = 0; c < 8; ++c)
            gload_lds16(gb + goff[c], lb + c * 1024);
    };

    // LDS read bases (per-lane, buffer 0); all reads = base + immediate
    const int koff_base = l15 * 512 + ((lg * 16) ^ ((l15 & 3) << 4));
    const int voff_base = 32768 + l15 * 64 + ((lg * 16) ^ (((l15 >> 1) & 3) << 4));

    f32x4 acc[16] = {};     // O^T: acc[dt][r] = O[d=dt*16+lg*4+r][q=l15]
    float m_run = -1e30f;
    float l_lane = 0.f;     // per-lane partial denominator; reduced in epilogue
    const float C = 0.09016844005556021f;   // (1/16)*log2(e)

    stage(0);
    __syncthreads();

    #pragma unroll 2
    for (int kt = 0; kt < 64; ++kt) {
        if (kt < 63) stage(kt + 1);   // loads fly across the whole compute phase

        const int cb = (kt & 1) << 14;          // constant per unrolled copy
        const char* kp = sm + (cb + koff_base);
        const char* vp = sm + (cb + voff_base);

        // ---- S^T = K * Q^T, 4 independent accumulation chains
        f32x4 s0a = {}, s0b = {}, s1a = {}, s1b = {};
        #pragma unroll
        for (int ks = 0; ks < 4; ++ks) {
            bf16x8 kf0 = *(const bf16x8*)(kp + ks * 64);
            bf16x8 kf1 = *(const bf16x8*)(kp + 8192 + ks * 64);
            s0a = __builtin_amdgcn_mfma_f32_16x16x32_bf16(kf0, qf[ks], s0a, 0, 0, 0);
            s1a = __builtin_amdgcn_mfma_f32_16x16x32_bf16(kf1, qf[ks], s1a, 0, 0, 0);
        }
        #pragma unroll
        for (int ks = 4; ks < 8; ++ks) {
            bf16x8 kf0 = *(const bf16x8*)(kp + ks * 64);
            bf16x8 kf1 = *(const bf16x8*)(kp + 8192 + ks * 64);
            s0b = __builtin_amdgcn_mfma_f32_16x16x32_bf16(kf0, qf[ks], s0b, 0, 0, 0);
            s1b = __builtin_amdgcn_mfma_f32_16x16x32_bf16(kf1, qf[ks], s1b, 0, 0, 0);
        }
        f32x4 st0 = s0a + s0b;
        f32x4 st1 = s1a + s1b;

        // ---- online softmax, shuffle-free fast path
        float p0 = fmaxf(fmaxf(st0[0], st0[1]), fmaxf(st0[2], st0[3]));
        float p1 = fmaxf(fmaxf(st1[0], st1[1]), fmaxf(st1[2], st1[3]));
        float lmax = fmaxf(p0, p1);

        if (__any(lmax > m_run + 16.f)) {   // rare after tile 0
            float rmax = lmax;
            rmax = fmaxf(rmax, __shfl_xor(rmax, 16, 64));
            rmax = fmaxf(rmax, __shfl_xor(rmax, 32, 64));
            float m_new = fmaxf(m_run, rmax);
            float rs = exp2f((m_run - m_new) * C);
            #pragma unroll
            for (int dt = 0; dt < 16; ++dt) acc[dt] *= rs;
            l_lane *= rs;
            m_run = m_new;
        }
        // P = exp2((S - m_run)*C) bounded by exp2(16*C) = e (bf16-safe)

        const float mc = m_run * C;
        float sum = 0.f;
        #pragma unroll
        for (int i = 0; i < 4; ++i) {
            float e0 = exp2f(st0[i] * C - mc);
            float e1 = exp2f(st1[i] * C - mc);
            st0[i] = e0; st1[i] = e1;
            sum += e0 + e1;
        }
        l_lane += sum;

        // ---- pack own P dwords (v_cvt_pk): dM_h = kv {M*16+lg*4+2h, +1} @ q=l15
        unsigned d00 = pack2bf(st0[0], st0[1]);
        unsigned d01 = pack2bf(st0[2], st0[3]);
        unsigned d10 = pack2bf(st1[0], st1[1]);
        unsigned d11 = pack2bf(st1[2], st1[3]);

        // ---- exchange to PV B-frag: lane needs P[q=l15][kv=lg*8 .. lg*8+7]
        unsigned own0 = (lg & 2) ? d10 : d00;
        unsigned own1 = (lg & 2) ? d11 : d01;
        unsigned cx0  = (lg & 2) ? d00 : d10;
        unsigned cx1  = (lg & 2) ? d01 : d11;
        unsigned r16_0 = __shfl_xor(own0, 16, 64);
        unsigned r16_1 = __shfl_xor(own1, 16, 64);
        unsigned r32_0 = __shfl_xor(cx0, 32, 64);
        unsigned r32_1 = __shfl_xor(cx1, 32, 64);
        unsigned r48_0 = __shfl_xor(cx0, 48, 64);
        unsigned r48_1 = __shfl_xor(cx1, 48, 64);
        union { unsigned u[4]; bf16x8 v; } pf;
        pf.u[0] = (lg == 0) ? own0 : (lg == 1) ? r48_0 : (lg == 2) ? r32_0 : r16_0;
        pf.u[1] = (lg == 0) ? own1 : (lg == 1) ? r48_1 : (lg == 2) ? r32_1 : r16_1;
        pf.u[2] = (lg == 0) ? r16_0 : (lg == 1) ? r32_0 : (lg == 2) ? r48_0 : own0;
        pf.u[3] = (lg == 0) ? r16_1 : (lg == 1) ? r32_1 : (lg == 2) ? r48_1 : own1;

        // ---- PV: acc[dt] += Vt_tile(dt) * P^T  (16 independent chains)
        #pragma unroll
        for (int dt = 0; dt < 16; ++dt) {
            bf16x8 vf = *(const bf16x8*)(vp + dt * 1024);
            acc[dt] = __builtin_amdgcn_mfma_f32_16x16x32_bf16(vf, pf.v, acc[dt], 0, 0, 0);
        }

        __syncthreads();   // stage loads have been in flight for the whole iter
    }

    // ---- deferred denominator reduce (row = lanes {l15, ^16, ^32, ^48})
    float l_row = l_lane;
    l_row += __shfl_xor(l_row, 16, 64);
    l_row += __shfl_xor(l_row, 32, 64);
    const float inv = 1.f / l_row;

    // ---- epilogue: O = acc * inv; transpose 64-d chunks via per-wave LDS
    float* ow = (float*)(sm + w * 4352);   // [16 q][68 f32]
    #pragma unroll
    for (int p = 0; p < 4; ++p) {
        #pragma unroll
        for (int d2 = 0; d2 < 4; ++d2) {
            const int dt = p * 4 + d2;
            #pragma unroll
            for (int r = 0; r < 4; ++r)
                ow[l15 * 68 + d2 * 16 + lg * 4 + r] = acc[dt][r] * inv;
        }
        const int row = lane >> 2;
        const int c0  = (lane & 3) * 16;
        #pragma unroll
        for (int i = 0; i < 4; ++i) {
            float4 v = *(const float4*)(ow + row * 68 + c0 + i * 4);
            *(float4*)(out + (tokbase + q0w + row) * 256 + p * 64 + c0 + i * 4) = v;
        }
    }
}

// ================================ launch ===================================
extern "C" void kernel_launch(void* const* d_in, const int* in_sizes, int n_in,
                              void* d_out, int out_size, void* d_ws, size_t ws_size,
                              hipStream_t stream) {
    (void)in_sizes; (void)n_in; (void)out_size; (void)ws_size;
    const float* x  = (const float*)d_in[0];
    const float* Wq = (const float*)d_in[1];
    const float* bq = (const float*)d_in[2];
    const float* Wk = (const float*)d_in[3];
    const float* bk = (const float*)d_in[4];
    const float* Wv = (const float*)d_in[5];
    const float* bv = (const float*)d_in[6];
    float* out = (float*)d_out;

    char* ws = (char*)d_ws;
    u16* xb  = (u16*)(ws);
    u16* wqb = (u16*)(ws + 16777216);
    u16* wkb = (u16*)(ws + 16908288);
    u16* wvb = (u16*)(ws + 17039360);
    u16* Qb  = (u16*)(ws + 17170432);
    u16* Kb  = (u16*)(ws + 33947648);
    u16* Vtb = (u16*)(ws + 50724864);

    cast_kernel<<<2048, 256, 0, stream>>>(x,  xb,  1048576);
    cast_kernel<<<64,   256, 0, stream>>>(Wq, wqb, 8192);
    cast_kernel<<<64,   256, 0, stream>>>(Wk, wkb, 8192);
    cast_kernel<<<64,   256, 0, stream>>>(Wv, wvb, 8192);

    proj_qk_kernel<<<dim3(4, 256), 256, 0, stream>>>(xb, wqb, wkb, bq, bk, Qb, Kb);
    proj_v_kernel<<<dim3(256, 2), 256, 0, stream>>>(wvb, xb, bv, Vtb);

    attn_kernel<<<dim3(32, 16), 256, 0, stream>>>(Qb, Kb, Vtb, out);
}

// Round 7
// 180.043 us; speedup vs baseline: 1.0092x; 1.0092x over previous
//
#include <hip/hip_runtime.h>
#include <hip/hip_bf16.h>
#include <stdint.h>

#define DEV __device__ __forceinline__

typedef __attribute__((ext_vector_type(8))) short bf16x8;
typedef __attribute__((ext_vector_type(4))) float f32x4;
typedef unsigned short u16;

// ---- async global->LDS, 16B per lane. lds dest must be wave-uniform base. ----
DEV void gload_lds16(const void* g, void* l) {
    typedef const __attribute__((address_space(1))) unsigned int* gp_t;
    typedef __attribute__((address_space(3))) unsigned int* lp_t;
    __builtin_amdgcn_global_load_lds((gp_t)(uintptr_t)g, (lp_t)(uint32_t)(uintptr_t)l, 16, 0, 0);
}

DEV u16 f2bf(float x) {
    union { __hip_bfloat16 h; u16 u; } c;
    c.h = __float2bfloat16(x);
    return c.u;
}
// packed f32x2 -> bf16x2 (v_cvt_pk_bf16_f32 path)
DEV unsigned pack2bf(float a, float b) {
    union { __hip_bfloat162 h2; unsigned u; } cv;
    cv.h2 = __float22bfloat162_rn(make_float2(a, b));
    return cv.u;
}

// ============================ cast fp32 -> bf16 ============================
__global__ void cast_kernel(const float* __restrict__ src, u16* __restrict__ dst, int n8) {
    int stride = gridDim.x * blockDim.x;
    for (int i = blockIdx.x * blockDim.x + threadIdx.x; i < n8; i += stride) {
        const float4* s = (const float4*)src + (size_t)i * 2;
        float4 a = s[0], b = s[1];
        union { u16 u[8]; uint4 v; } o;
        o.u[0] = f2bf(a.x); o.u[1] = f2bf(a.y); o.u[2] = f2bf(a.z); o.u[3] = f2bf(a.w);
        o.u[4] = f2bf(b.x); o.u[5] = f2bf(b.y); o.u[6] = f2bf(b.z); o.u[7] = f2bf(b.w);
        *((uint4*)dst + i) = o.v;
    }
}

// ============================ projection GEMM ==============================
DEV void gemm_body(const u16* A, const u16* Bw, const float* bias, int bias_row,
                   u16* out, int out_pitch)
{
    __shared__ char smA[16384];
    __shared__ char smB[16384];
    const int lane = threadIdx.x & 63;
    const int w    = threadIdx.x >> 6;
    const int wr   = w >> 1, wc = w & 1;
    const int l15  = lane & 15, lg = lane >> 4;

    f32x4 acc[4][4] = {};
    const char* ag = (const char*)A;
    const char* bg = (const char*)Bw;

    for (int kt = 0; kt < 4; ++kt) {
        __syncthreads();
        #pragma unroll
        for (int c = 0; c < 8; ++c) {
            int ch    = w * 8 + c;
            int loc   = ch & 15;
            int p     = loc * 1024 + lane * 16;
            int row   = p >> 7;
            int inner = (p & 127) ^ ((row & 7) << 4);
            const char* src = (ch < 16 ? ag : bg) + row * 512 + kt * 128 + inner;
            char* dst = (ch < 16 ? smA : smB) + loc * 1024;
            gload_lds16(src, dst);
        }
        __syncthreads();
        #pragma unroll
        for (int ks = 0; ks < 2; ++ks) {
            bf16x8 af[4], bfr[4];
            #pragma unroll
            for (int mi = 0; mi < 4; ++mi) {
                int row = wr * 64 + mi * 16 + l15;
                af[mi] = *(const bf16x8*)(smA + ((row * 128 + ks * 64 + lg * 16) ^ ((row & 7) << 4)));
            }
            #pragma unroll
            for (int ni = 0; ni < 4; ++ni) {
                int row = wc * 64 + ni * 16 + l15;
                bfr[ni] = *(const bf16x8*)(smB + ((row * 128 + ks * 64 + lg * 16) ^ ((row & 7) << 4)));
            }
            #pragma unroll
            for (int mi = 0; mi < 4; ++mi)
                #pragma unroll
                for (int ni = 0; ni < 4; ++ni)
                    acc[mi][ni] = __builtin_amdgcn_mfma_f32_16x16x32_bf16(af[mi], bfr[ni], acc[mi][ni], 0, 0, 0);
        }
    }
    #pragma unroll
    for (int mi = 0; mi < 4; ++mi) {
        #pragma unroll
        for (int ni = 0; ni < 4; ++ni) {
            int n_l  = wc * 64 + ni * 16 + l15;
            float bn = bias_row ? 0.f : bias[n_l];
            #pragma unroll
            for (int r = 0; r < 4; ++r) {
                int row  = wr * 64 + mi * 16 + lg * 4 + r;
                float bb = bias_row ? bias[row] : bn;
                out[(size_t)row * out_pitch + n_l] = f2bf(acc[mi][ni][r] + bb);
            }
        }
    }
}

__global__ __launch_bounds__(256) void proj_qk_kernel(
    const u16* xb, const u16* wqb, const u16* wkb,
    const float* bq, const float* bk, u16* Q, u16* K)
{
    int n0 = blockIdx.x * 128;
    int m0 = blockIdx.y * 128;
    bool isK = n0 >= 256;
    int  nl  = n0 & 255;
    gemm_body(xb + (size_t)m0 * 256, (isK ? wkb : wqb) + (size_t)nl * 256,
              (isK ? bk : bq) + nl, 0,
              (isK ? K : Q) + (size_t)m0 * 256 + nl, 256);
}

__global__ __launch_bounds__(256) void proj_v_kernel(
    const u16* wvb, const u16* xb, const float* bv, u16* Vt)
{
    int n0 = blockIdx.x * 128;
    int m0 = blockIdx.y * 128;
    gemm_body(wvb + (size_t)m0 * 256, xb + (size_t)n0 * 256, bv + m0, 1,
              Vt + (size_t)m0 * 32768 + n0, 32768);
}

// ============================ fused attention ==============================
// 4 waves x 16 q-rows = 64 q/block, grid 512 = 2 blocks/CU. KVBLK=32 dbuf.
// VALU-diet version: all LDS read addresses are 1 base VGPR + instruction
// immediates (K swizzle = (row&3)<<4, bits 4-5 only, so ks*64 / dt*1024 terms
// stay immediate-foldable); staging uses precomputed per-lane 32-bit offsets
// + uniform scalar base advance; bf16 pack via v_cvt_pk; QK chain split 4-way.
__global__ __launch_bounds__(256, 2) void attn_kernel(
    const u16* __restrict__ Q, const u16* __restrict__ K,
    const u16* __restrict__ Vt, float* __restrict__ out)
{
    __shared__ char sm[65536];
    // K tile t: sm + (t&1)*16384:         [32 kv][512B], byte ^= (row&3)<<4
    // V tile t: sm + 32768 + (t&1)*16384: [256 d][64B],  byte ^= ((row>>1)&3)<<4

    const int lane = threadIdx.x & 63;
    const int w    = threadIdx.x >> 6;
    const int l15  = lane & 15;
    const int lg   = lane >> 4;

    // XCD batch-confinement: XCD (lin%8) serves 2 batches -> K/V (4MB) L2-resident
    const int lin = blockIdx.y * 32 + blockIdx.x;
    const int b   = (lin & 7) * 2 + ((lin >> 3) & 1);
    const int qt  = lin >> 4;
    const size_t tokbase = (size_t)b * 2048;
    const int q0w = qt * 64 + w * 16;

    // Q fragments (B-operand): lane holds Q[q0w+l15][ks*32 + lg*8 + j]
    bf16x8 qf[8];
    {
        const char* qrow = (const char*)(Q + (tokbase + q0w + l15) * 256);
        #pragma unroll
        for (int ks = 0; ks < 8; ++ks)
            qf[ks] = *(const bf16x8*)(qrow + ks * 64 + lg * 16);
    }

    // ---- staging setup: per-lane invariant offsets, uniform per-tile base bump
    uint32_t goff[8];
    const char* gbase;   // uniform source base for tile 0
    int gstep;           // uniform source bytes per tile
    char* ldst;          // wave-uniform LDS dst base (buffer 0)
    if (w < 2) {         // waves 0,1 stage K (rows 0..31, 512B each)
        #pragma unroll
        for (int c = 0; c < 8; ++c) {
            int row = (w * 8 + c) * 2 + (lane >> 5);
            goff[c] = row * 512 + (((lane & 31) * 16) ^ ((row & 3) << 4));
        }
        gbase = (const char*)K + tokbase * 512;
        gstep = 32 * 512;
        ldst  = sm + w * 8192;
    } else {             // waves 2,3 stage Vt (256 d-rows x 64B slice)
        #pragma unroll
        for (int c = 0; c < 8; ++c) {
            int row = ((w - 2) * 8 + c) * 16 + (lane >> 2);
            goff[c] = row * 65536 + (((lane & 3) * 16) ^ (((row >> 1) & 3) << 4));
        }
        gbase = (const char*)Vt + tokbase * 2;
        gstep = 32 * 2;
        ldst  = sm + 32768 + (w - 2) * 8192;
    }
    auto stage = [&](int t) {
        const char* gb = gbase + (size_t)t * gstep;   // uniform (SALU)
        char* lb = ldst + ((t & 1) << 14);
        #pragma unroll
        for (int c = 0; c < 8; ++c)
            gload_lds16(gb + goff[c], lb + c * 1024);
    };

    // LDS read bases (per-lane, buffer 0); all reads = base + immediate
    const int koff_base = l15 * 512 + ((lg * 16) ^ ((l15 & 3) << 4));
    const int voff_base = 32768 + l15 * 64 + ((lg * 16) ^ (((l15 >> 1) & 3) << 4));

    f32x4 acc[16] = {};     // O^T: acc[dt][r] = O[d=dt*16+lg*4+r][q=l15]
    float m_run = -1e30f;
    float l_lane = 0.f;     // per-lane partial denominator; reduced in epilogue
    const float C = 0.09016844005556021f;   // (1/16)*log2(e)

    stage(0);
    __syncthreads();

    #pragma unroll 2
    for (int kt = 0; kt < 64; ++kt) {
        if (kt < 63) stage(kt + 1);   // loads fly across the whole compute phase

        const int cb = (kt & 1) << 14;          // constant per unrolled copy
        const char* kp = sm + (cb + koff_base);
        const char* vp = sm + (cb + voff_base);

        // ---- S^T = K * Q^T, 4 independent accumulation chains
        f32x4 s0a = {}, s0b = {}, s1a = {}, s1b = {};
        #pragma unroll
        for (int ks = 0; ks < 4; ++ks) {
            bf16x8 kf0 = *(const bf16x8*)(kp + ks * 64);
            bf16x8 kf1 = *(const bf16x8*)(kp + 8192 + ks * 64);
            s0a = __builtin_amdgcn_mfma_f32_16x16x32_bf16(kf0, qf[ks], s0a, 0, 0, 0);
            s1a = __builtin_amdgcn_mfma_f32_16x16x32_bf16(kf1, qf[ks], s1a, 0, 0, 0);
        }
        #pragma unroll
        for (int ks = 4; ks < 8; ++ks) {
            bf16x8 kf0 = *(const bf16x8*)(kp + ks * 64);
            bf16x8 kf1 = *(const bf16x8*)(kp + 8192 + ks * 64);
            s0b = __builtin_amdgcn_mfma_f32_16x16x32_bf16(kf0, qf[ks], s0b, 0, 0, 0);
            s1b = __builtin_amdgcn_mfma_f32_16x16x32_bf16(kf1, qf[ks], s1b, 0, 0, 0);
        }
        f32x4 st0 = s0a + s0b;
        f32x4 st1 = s1a + s1b;

        // ---- online softmax, shuffle-free fast path
        float p0 = fmaxf(fmaxf(st0[0], st0[1]), fmaxf(st0[2], st0[3]));
        float p1 = fmaxf(fmaxf(st1[0], st1[1]), fmaxf(st1[2], st1[3]));
        float lmax = fmaxf(p0, p1);

        if (__any(lmax > m_run + 16.f)) {   // rare after tile 0
            float rmax = lmax;
            rmax = fmaxf(rmax, __shfl_xor(rmax, 16, 64));
            rmax = fmaxf(rmax, __shfl_xor(rmax, 32, 64));
            float m_new = fmaxf(m_run, rmax);
            float rs = exp2f((m_run - m_new) * C);
            #pragma unroll
            for (int dt = 0; dt < 16; ++dt) acc[dt] *= rs;
            l_lane *= rs;
            m_run = m_new;
        }
        // P = exp2((S - m_run)*C) bounded by exp2(16*C) = e (bf16-safe)

        const float mc = m_run * C;
        float sum = 0.f;
        #pragma unroll
        for (int i = 0; i < 4; ++i) {
            float e0 = exp2f(st0[i] * C - mc);
            float e1 = exp2f(st1[i] * C - mc);
            st0[i] = e0; st1[i] = e1;
            sum += e0 + e1;
        }
        l_lane += sum;

        // ---- pack own P dwords (v_cvt_pk): dM_h = kv {M*16+lg*4+2h, +1} @ q=l15
        unsigned d00 = pack2bf(st0[0], st0[1]);
        unsigned d01 = pack2bf(st0[2], st0[3]);
        unsigned d10 = pack2bf(st1[0], st1[1]);
        unsigned d11 = pack2bf(st1[2], st1[3]);

        // ---- exchange to PV B-frag: lane needs P[q=l15][kv=lg*8 .. lg*8+7]
        unsigned own0 = (lg & 2) ? d10 : d00;
        unsigned own1 = (lg & 2) ? d11 : d01;
        unsigned cx0  = (lg & 2) ? d00 : d10;
        unsigned cx1  = (lg & 2) ? d01 : d11;
        unsigned r16_0 = __shfl_xor(own0, 16, 64);
        unsigned r16_1 = __shfl_xor(own1, 16, 64);
        unsigned r32_0 = __shfl_xor(cx0, 32, 64);
        unsigned r32_1 = __shfl_xor(cx1, 32, 64);
        unsigned r48_0 = __shfl_xor(cx0, 48, 64);
        unsigned r48_1 = __shfl_xor(cx1, 48, 64);
        union { unsigned u[4]; bf16x8 v; } pf;
        pf.u[0] = (lg == 0) ? own0 : (lg == 1) ? r48_0 : (lg == 2) ? r32_0 : r16_0;
        pf.u[1] = (lg == 0) ? own1 : (lg == 1) ? r48_1 : (lg == 2) ? r32_1 : r16_1;
        pf.u[2] = (lg == 0) ? r16_0 : (lg == 1) ? r32_0 : (lg == 2) ? r48_0 : own0;
        pf.u[3] = (lg == 0) ? r16_1 : (lg == 1) ? r32_1 : (lg == 2) ? r48_1 : own1;

        // ---- PV: acc[dt] += Vt_tile(dt) * P^T  (16 independent chains)
        #pragma unroll
        for (int dt = 0; dt < 16; ++dt) {
            bf16x8 vf = *(const bf16x8*)(vp + dt * 1024);
            acc[dt] = __builtin_amdgcn_mfma_f32_16x16x32_bf16(vf, pf.v, acc[dt], 0, 0, 0);
        }

        __syncthreads();   // stage loads have been in flight for the whole iter
    }

    // ---- deferred denominator reduce (row = lanes {l15, ^16, ^32, ^48})
    float l_row = l_lane;
    l_row += __shfl_xor(l_row, 16, 64);
    l_row += __shfl_xor(l_row, 32, 64);
    const float inv = 1.f / l_row;

    // ---- epilogue: O = acc * inv; transpose 64-d chunks via per-wave LDS
    float* ow = (float*)(sm + w * 4352);   // [16 q][68 f32]
    #pragma unroll
    for (int p = 0; p < 4; ++p) {
        #pragma unroll
        for (int d2 = 0; d2 < 4; ++d2) {
            const int dt = p * 4 + d2;
            #pragma unroll
            for (int r = 0; r < 4; ++r)
                ow[l15 * 68 + d2 * 16 + lg * 4 + r] = acc[dt][r] * inv;
        }
        const int row = lane >> 2;
        const int c0  = (lane & 3) * 16;
        #pragma unroll
        for (int i = 0; i < 4; ++i) {
            float4 v = *(const float4*)(ow + row * 68 + c0 + i * 4);
            *(float4*)(out + (tokbase + q0w + row) * 256 + p * 64 + c0 + i * 4) = v;
        }
    }
}

// ================================ launch ===================================
extern "C" void kernel_launch(void* const* d_in, const int* in_sizes, int n_in,
                              void* d_out, int out_size, void* d_ws, size_t ws_size,
                              hipStream_t stream) {
    (void)in_sizes; (void)n_in; (void)out_size; (void)ws_size;
    const float* x  = (const float*)d_in[0];
    const float* Wq = (const float*)d_in[1];
    const float* bq = (const float*)d_in[2];
    const float* Wk = (const float*)d_in[3];
    const float* bk = (const float*)d_in[4];
    const float* Wv = (const float*)d_in[5];
    const float* bv = (const float*)d_in[6];
    float* out = (float*)d_out;

    char* ws = (char*)d_ws;
    u16* xb  = (u16*)(ws);
    u16* wqb = (u16*)(ws + 16777216);
    u16* wkb = (u16*)(ws + 16908288);
    u16* wvb = (u16*)(ws + 17039360);
    u16* Qb  = (u16*)(ws + 17170432);
    u16* Kb  = (u16*)(ws + 33947648);
    u16* Vtb = (u16*)(ws + 50724864);

    cast_kernel<<<2048, 256, 0, stream>>>(x,  xb,  1048576);
    cast_kernel<<<64,   256, 0, stream>>>(Wq, wqb, 8192);
    cast_kernel<<<64,   256, 0, stream>>>(Wk, wkb, 8192);
    cast_kernel<<<64,   256, 0, stream>>>(Wv, wvb, 8192);

    proj_qk_kernel<<<dim3(4, 256), 256, 0, stream>>>(xb, wqb, wkb, bq, bk, Qb, Kb);
    proj_v_kernel<<<dim3(256, 2), 256, 0, stream>>>(wvb, xb, bv, Vtb);

    attn_kernel<<<dim3(32, 16), 256, 0, stream>>>(Qb, Kb, Vtb, out);
}